// Round 1
// 122.127 us; speedup vs baseline: 1.1351x; 1.1351x over previous
//
#include <hip/hip_runtime.h>
#include <hip/hip_bf16.h>

#define N_NODES 8192
#define DIN     512
#define DOUT    256
#define ALPHA   0.2f
#define LOG2E   1.4426950408889634f

typedef __bf16 bf16x8 __attribute__((ext_vector_type(8)));
typedef __bf16 bf16x4 __attribute__((ext_vector_type(4)));
typedef float  f32x4  __attribute__((ext_vector_type(4)));
typedef int    i32x4  __attribute__((ext_vector_type(4)));
typedef unsigned u32x4 __attribute__((ext_vector_type(4)));

// ---------------------------------------------------------------------------
// A0: repack weight f32 [512][256] -> wB bf16 fragment layout. Zeroes kmaxkey.
__global__ __launch_bounds__(256) void k_repack_w(const float* __restrict__ w,
                                                  bf16x8* __restrict__ wB,
                                                  unsigned* __restrict__ kmaxkey) {
    if (blockIdx.x == 0 && threadIdx.x == 0) *kmaxkey = 0u;
    int u = blockIdx.x * 256 + threadIdx.x;   // 16384 units
    int lane = u & 63, t = u >> 6;
    int nt = t & 15, kt = t >> 4;
    int k0 = kt * 32 + (lane >> 4) * 8;
    int col = nt * 16 + (lane & 15);
    bf16x8 r;
#pragma unroll
    for (int i = 0; i < 8; ++i) r[i] = (__bf16)w[(size_t)(k0 + i) * DOUT + col];
    wB[u] = r;
}

// ---------------------------------------------------------------------------
// A1 (fused): v = node @ weight in registers; emits vB fragments (LDS bounce),
// Q/K scalars, global K-max. Grid 256 = 1 blk/CU -> every stall exposed, so:
// node prefetched depth-2, wB fragments depth-1.
__global__ __launch_bounds__(256) void k_gemm1f(const float* __restrict__ node,
                                                const bf16x8* __restrict__ wB,
                                                const float* __restrict__ a,
                                                bf16x8* __restrict__ vBo,
                                                float* __restrict__ Q, float* __restrict__ K,
                                                unsigned* __restrict__ kmaxkey) {
    __shared__ __bf16 vsh[32][260];   // +4 pad
    __shared__ float qksh[32][2];
    int lane = threadIdx.x & 63, w = threadIdx.x >> 6;
    int r15 = lane & 15, g = lane >> 4;
    int nh = w & 1, rh = w >> 1;
    int rowbase = blockIdx.x * 32;
    int myrow = rowbase + rh * 16 + r15;
    const float* np = node + (size_t)myrow * DIN + g * 8;

    f32x4 acc[8];
#pragma unroll
    for (int j = 0; j < 8; ++j) acc[j] = (f32x4){0.f, 0.f, 0.f, 0.f};

    f32x4 c0 = *(const f32x4*)np;
    f32x4 c1 = *(const f32x4*)(np + 4);
    f32x4 c2 = *(const f32x4*)(np + 32);
    f32x4 c3 = *(const f32x4*)(np + 36);
    const bf16x8* wp = wB + (size_t)(nh * 8) * 64 + lane;
    bf16x8 fr0 = wp[0], fr1 = wp[64], fr2 = wp[128], fr3 = wp[192];
    bf16x8 fr4 = wp[256], fr5 = wp[320], fr6 = wp[384], fr7 = wp[448];

    for (int kt = 0; kt < 16; ++kt) {
        f32x4 u0 = c0, u1 = c1;
        c0 = c2; c1 = c3;
        if (kt + 2 < 16) {
            c2 = *(const f32x4*)(np + (kt + 2) * 32);
            c3 = *(const f32x4*)(np + (kt + 2) * 32 + 4);
        }
        bf16x8 f0 = fr0, f1 = fr1, f2 = fr2, f3 = fr3;
        bf16x8 f4 = fr4, f5 = fr5, f6 = fr6, f7 = fr7;
        if (kt + 1 < 16) {
            const bf16x8* wn = wB + ((size_t)(kt + 1) * 16 + nh * 8) * 64 + lane;
            fr0 = wn[0]; fr1 = wn[64]; fr2 = wn[128]; fr3 = wn[192];
            fr4 = wn[256]; fr5 = wn[320]; fr6 = wn[384]; fr7 = wn[448];
        }
        bf16x8 af;
#pragma unroll
        for (int i = 0; i < 4; ++i) { af[i] = (__bf16)u0[i]; af[i + 4] = (__bf16)u1[i]; }
        acc[0] = __builtin_amdgcn_mfma_f32_16x16x32_bf16(af, f0, acc[0], 0, 0, 0);
        acc[1] = __builtin_amdgcn_mfma_f32_16x16x32_bf16(af, f1, acc[1], 0, 0, 0);
        acc[2] = __builtin_amdgcn_mfma_f32_16x16x32_bf16(af, f2, acc[2], 0, 0, 0);
        acc[3] = __builtin_amdgcn_mfma_f32_16x16x32_bf16(af, f3, acc[3], 0, 0, 0);
        acc[4] = __builtin_amdgcn_mfma_f32_16x16x32_bf16(af, f4, acc[4], 0, 0, 0);
        acc[5] = __builtin_amdgcn_mfma_f32_16x16x32_bf16(af, f5, acc[5], 0, 0, 0);
        acc[6] = __builtin_amdgcn_mfma_f32_16x16x32_bf16(af, f6, acc[6], 0, 0, 0);
        acc[7] = __builtin_amdgcn_mfma_f32_16x16x32_bf16(af, f7, acc[7], 0, 0, 0);
    }

    // ---- Q/K partial dots over this wave's 8 nt-columns ----
    float qp0 = 0.f, qp1 = 0.f, qp2 = 0.f, qp3 = 0.f;
    float kp0 = 0.f, kp1 = 0.f, kp2 = 0.f, kp3 = 0.f;
#pragma unroll
    for (int j = 0; j < 8; ++j) {
        int col = (nh * 8 + j) * 16 + r15;
        float a1 = a[col], a2 = a[DOUT + col];
        qp0 += acc[j][0] * a1; qp1 += acc[j][1] * a1;
        qp2 += acc[j][2] * a1; qp3 += acc[j][3] * a1;
        kp0 += acc[j][0] * a2; kp1 += acc[j][1] * a2;
        kp2 += acc[j][2] * a2; kp3 += acc[j][3] * a2;
    }
#pragma unroll
    for (int m = 1; m < 16; m <<= 1) {
        qp0 += __shfl_xor(qp0, m); qp1 += __shfl_xor(qp1, m);
        qp2 += __shfl_xor(qp2, m); qp3 += __shfl_xor(qp3, m);
        kp0 += __shfl_xor(kp0, m); kp1 += __shfl_xor(kp1, m);
        kp2 += __shfl_xor(kp2, m); kp3 += __shfl_xor(kp3, m);
    }

#pragma unroll
    for (int j = 0; j < 8; ++j)
#pragma unroll
        for (int r = 0; r < 4; ++r)
            vsh[rh * 16 + g * 4 + r][(nh * 8 + j) * 16 + r15] = (__bf16)acc[j][r];
    if (nh == 0 && r15 == 0) {
        int rl = rh * 16 + g * 4;
        qksh[rl + 0][0] = qp0; qksh[rl + 1][0] = qp1; qksh[rl + 2][0] = qp2; qksh[rl + 3][0] = qp3;
        qksh[rl + 0][1] = kp0; qksh[rl + 1][1] = kp1; qksh[rl + 2][1] = kp2; qksh[rl + 3][1] = kp3;
    }
    __syncthreads();
    if (nh == 1 && r15 == 0) {
        int rl = rh * 16 + g * 4;
        int rw = rowbase + rl;
        float q0 = qp0 + qksh[rl + 0][0], q1 = qp1 + qksh[rl + 1][0];
        float q2 = qp2 + qksh[rl + 2][0], q3 = qp3 + qksh[rl + 3][0];
        float k0 = kp0 + qksh[rl + 0][1], k1 = kp1 + qksh[rl + 1][1];
        float k2 = kp2 + qksh[rl + 2][1], k3 = kp3 + qksh[rl + 3][1];
        Q[rw + 0] = q0; Q[rw + 1] = q1; Q[rw + 2] = q2; Q[rw + 3] = q3;
        K[rw + 0] = k0; K[rw + 1] = k1; K[rw + 2] = k2; K[rw + 3] = k3;
        float km = fmaxf(fmaxf(k0, k1), fmaxf(k2, k3));
        unsigned bits = __float_as_uint(km);
        unsigned key = (bits & 0x80000000u) ? ~bits : (bits | 0x80000000u);
        atomicMax(kmaxkey, key);
    }
#pragma unroll
    for (int uu = 0; uu < 4; ++uu) {
        int nt = w * 4 + uu;
        bf16x8 t;
#pragma unroll
        for (int i = 0; i < 8; ++i) t[i] = vsh[g * 8 + i][nt * 16 + r15];
        vBo[((size_t)blockIdx.x * 16 + nt) * 64 + lane] = t;
    }
}

// ---------------------------------------------------------------------------
// B: fused masked-softmax-numerator GEMM, adj streaming SOFTWARE-PIPELINED
// into the MFMA loop (round 6 change). Previously: bulk phase-1 bitmask pack
// then phase-2 compute -> the whole resident grid streamed 268 MB of adj with
// zero compute overlap, then computed with zero HBM overlap. Now each thread
// packs ONE mask dword (32 adj ints, 8x i32x4 loads) per 4-BODYM group,
// staged 2 groups ahead (loads issued 3 ahead). The existing per-BODYM
// lgkmcnt(0)+s_barrier fences the Ms store (iter G, group G+2) against its
// first read (iter G+1 Wn prefetch) with 2 intervening barriers.
// P_ij = adj_ij*exp(lrelu(Qi+Kj)-c_i), c_i = lrelu(Qi+Kmax) fixed shift ->
// j-split partials combine by addition. Epilogue: bf16 permuted partials.
// launch_bounds(256,2): guarantee 2 blocks/CU so sibling-block VALU/MFMA
// fills barrier/latency stalls.
template<int JS>
__global__ __launch_bounds__(256, 2) void k_attn(const int* __restrict__ adj,
                                                 const bf16x8* __restrict__ vBg,
                                                 const float* __restrict__ Q,
                                                 const float* __restrict__ K,
                                                 const unsigned* __restrict__ kmaxkey,
                                                 __bf16* __restrict__ accB,
                                                 float* __restrict__ Sp) {
    constexpr int JR   = N_NODES / JS;
    constexpr int BIT  = JR / 32;          // mask dwords per row (32 for JS=8)
    constexpr int NG   = BIT / 4;          // 4-BODYM groups (8 for JS=8)
    constexpr int MSTR = BIT + 4;          // pad: <=2-way bank = free
    __shared__ float    Ks[JR];
    __shared__ unsigned Ms[64][MSTR];
    __shared__ bf16x8   pT[2][4][64];

    int bid = blockIdx.x;
    int rb = bid / JS, p = bid % JS;       // p == XCD id (grid % 8 == 0)
    int lane = threadIdx.x & 63, w = threadIdx.x >> 6;
    int r15 = lane & 15, g = lane >> 4;
    int rowbase = rb * 64;
    int prow = rowbase + w * 16 + r15;
    int j0 = p * JR;

    for (int s = threadIdx.x * 4; s < JR; s += 1024)
        *(f32x4*)&Ks[s] = *(const f32x4*)&K[j0 + s];

    // mask-pack thread mapping: thread t owns row t>>2, dword (group*4 + (t&3))
    const int t = threadIdx.x;
    const int mrow = t >> 2, msub = t & 3;
    const int* abase = adj + (size_t)(rowbase + mrow) * N_NODES + j0;

#define ISSUE8(L, DC) { const int* src_ = abase + (DC) * 32;                     \
    _Pragma("unroll") for (int q = 0; q < 8; ++q) L[q] = *(const i32x4*)(src_ + q * 4); }
#define PACK32(L) ({ unsigned m_ = 0u;                                           \
    _Pragma("unroll") for (int q = 0; q < 8; ++q) {                              \
        m_ |= (L[q][0] != 0 ? 1u : 0u) << (q * 4 + 0);                           \
        m_ |= (L[q][1] != 0 ? 1u : 0u) << (q * 4 + 1);                           \
        m_ |= (L[q][2] != 0 ? 1u : 0u) << (q * 4 + 2);                           \
        m_ |= (L[q][3] != 0 ? 1u : 0u) << (q * 4 + 3); } m_; })

    // prologue: pack groups 0,1; leave group-2 loads in flight
    i32x4 La[8];
    {
        i32x4 Lb[8];
        ISSUE8(La, msub)
        ISSUE8(Lb, 4 + msub)
        Ms[mrow][msub] = PACK32(La);
        Ms[mrow][4 + msub] = PACK32(Lb);
    }
    ISSUE8(La, 8 + msub)

    float qi = Q[prow];
    unsigned kk = *kmaxkey;
    unsigned kb = (kk & 0x80000000u) ? (kk ^ 0x80000000u) : ~kk;
    float kmax = __uint_as_float(kb);
    float t0 = qi + kmax;
    float c2 = fmaxf(t0, ALPHA * t0) * LOG2E;
    // lrelu+shift folded: exp2(max(kj*L + A1, kj*(aL) + A2))
    float qiL = qi * LOG2E;
    float A1 = qiL - c2;
    float A2 = ALPHA * qiL - c2;

    const bf16x8* vbp = vBg + ((size_t)(p * BIT) * 16 + w * 4) * 64 + lane;

    f32x4 acc[4][4];
#pragma unroll
    for (int m = 0; m < 4; ++m)
#pragma unroll
        for (int n = 0; n < 4; ++n) acc[m][n] = (f32x4){0.f, 0.f, 0.f, 0.f};
    float sl = 0.f;

    // Ks + Ms groups 0,1 ready. Raw barrier (NOT __syncthreads: that would
    // vmcnt(0)-drain the in-flight group-2 adj loads).
    asm volatile("s_waitcnt lgkmcnt(0)" ::: "memory");
    __builtin_amdgcn_s_barrier();
    asm volatile("" ::: "memory");

    // prefetch: mask dwords for steps 0..3 (row = w*16+r15); vB depth-2
    u32x4 Wc = *(const u32x4*)&Ms[w * 16 + r15][0];
    bf16x8 vS0 = vbp[0],    vS1 = vbp[64],   vS2 = vbp[128],  vS3 = vbp[192];
    bf16x8 vT0 = vbp[1024], vT1 = vbp[1088], vT2 = vbp[1152], vT3 = vbp[1216];

#define BODYM(W32, V0, V1, V2, V3, BUF, itv)                                    \
    {                                                                           \
        bf16x8 b0 = V0, b1 = V1, b2 = V2, b3 = V3;                              \
        if ((itv) + 2 < BIT) {                                                  \
            V0 = vbp[((itv) + 2) * 1024];       V1 = vbp[((itv) + 2) * 1024 + 64];  \
            V2 = vbp[((itv) + 2) * 1024 + 128]; V3 = vbp[((itv) + 2) * 1024 + 192]; \
        }                                                                       \
        f32x4 q0 = *(const f32x4*)&Ks[(itv) * 32 + g * 8];                      \
        f32x4 q1 = *(const f32x4*)&Ks[(itv) * 32 + g * 8 + 4];                  \
        unsigned wsh = (W32) >> (g * 8);                                        \
        bf16x8 af;                                                              \
        _Pragma("unroll")                                                       \
        for (int i = 0; i < 8; ++i) {                                           \
            float kj = (i < 4) ? q0[i] : q1[i - 4];                             \
            float f1 = __builtin_fmaf(kj, LOG2E, A1);                           \
            float f2 = __builtin_fmaf(kj, ALPHA * LOG2E, A2);                   \
            float pv = __builtin_amdgcn_exp2f(fmaxf(f1, f2));                   \
            pv = (wsh & (1u << i)) ? pv : 0.f;                                  \
            sl += pv;                                                           \
            af[i] = (__bf16)pv;                                                 \
        }                                                                       \
        pT[BUF][w][lane] = af;                                                  \
        asm volatile("s_waitcnt lgkmcnt(0)" ::: "memory");                      \
        __builtin_amdgcn_s_barrier();                                           \
        asm volatile("" ::: "memory");                                         \
        bf16x8 pa0 = pT[BUF][0][lane], pa1 = pT[BUF][1][lane];                  \
        bf16x8 pa2 = pT[BUF][2][lane], pa3 = pT[BUF][3][lane];                  \
        acc[0][0] = __builtin_amdgcn_mfma_f32_16x16x32_bf16(pa0, b0, acc[0][0], 0, 0, 0); \
        acc[0][1] = __builtin_amdgcn_mfma_f32_16x16x32_bf16(pa0, b1, acc[0][1], 0, 0, 0); \
        acc[0][2] = __builtin_amdgcn_mfma_f32_16x16x32_bf16(pa0, b2, acc[0][2], 0, 0, 0); \
        acc[0][3] = __builtin_amdgcn_mfma_f32_16x16x32_bf16(pa0, b3, acc[0][3], 0, 0, 0); \
        acc[1][0] = __builtin_amdgcn_mfma_f32_16x16x32_bf16(pa1, b0, acc[1][0], 0, 0, 0); \
        acc[1][1] = __builtin_amdgcn_mfma_f32_16x16x32_bf16(pa1, b1, acc[1][1], 0, 0, 0); \
        acc[1][2] = __builtin_amdgcn_mfma_f32_16x16x32_bf16(pa1, b2, acc[1][2], 0, 0, 0); \
        acc[1][3] = __builtin_amdgcn_mfma_f32_16x16x32_bf16(pa1, b3, acc[1][3], 0, 0, 0); \
        acc[2][0] = __builtin_amdgcn_mfma_f32_16x16x32_bf16(pa2, b0, acc[2][0], 0, 0, 0); \
        acc[2][1] = __builtin_amdgcn_mfma_f32_16x16x32_bf16(pa2, b1, acc[2][1], 0, 0, 0); \
        acc[2][2] = __builtin_amdgcn_mfma_f32_16x16x32_bf16(pa2, b2, acc[2][2], 0, 0, 0); \
        acc[2][3] = __builtin_amdgcn_mfma_f32_16x16x32_bf16(pa2, b3, acc[2][3], 0, 0, 0); \
        acc[3][0] = __builtin_amdgcn_mfma_f32_16x16x32_bf16(pa3, b0, acc[3][0], 0, 0, 0); \
        acc[3][1] = __builtin_amdgcn_mfma_f32_16x16x32_bf16(pa3, b1, acc[3][1], 0, 0, 0); \
        acc[3][2] = __builtin_amdgcn_mfma_f32_16x16x32_bf16(pa3, b2, acc[3][2], 0, 0, 0); \
        acc[3][3] = __builtin_amdgcn_mfma_f32_16x16x32_bf16(pa3, b3, acc[3][3], 0, 0, 0); \
    }

    for (int G = 0; G < NG; ++G) {
        const int it4 = G * 4;
        u32x4 Wn = Wc;
        if (G + 1 < NG) Wn = *(const u32x4*)&Ms[w * 16 + r15][it4 + 4];
        BODYM(Wc[0], vS0, vS1, vS2, vS3, 0, it4 + 0)
        BODYM(Wc[1], vT0, vT1, vT2, vT3, 1, it4 + 1)
        // staged adj pack: store group G+2 (loads issued at iter G-1),
        // then issue loads for group G+3. Fenced by the two following
        // BODYM barriers before iter G+1 reads group G+2 via Wn.
        if (G + 2 < NG) {
            Ms[mrow][(G + 2) * 4 + msub] = PACK32(La);
            if (G + 3 < NG) ISSUE8(La, (G + 3) * 4 + msub)
        }
        BODYM(Wc[2], vS0, vS1, vS2, vS3, 0, it4 + 2)
        BODYM(Wc[3], vT0, vT1, vT2, vT3, 1, it4 + 3)
        Wc = Wn;
    }
#undef BODYM
#undef ISSUE8
#undef PACK32

    sl += __shfl_xor(sl, 16);
    sl += __shfl_xor(sl, 32);
    if (g == 0) Sp[(size_t)p * N_NODES + prow] = sl;

    __bf16* apb = accB + ((size_t)p * N_NODES + rowbase) * DOUT;
#pragma unroll
    for (int m = 0; m < 4; ++m)
#pragma unroll
        for (int r = 0; r < 4; ++r) {
            bf16x4 t2;
#pragma unroll
            for (int n = 0; n < 4; ++n) t2[n] = (__bf16)acc[m][n][r];
            *(bf16x4*)&apb[(size_t)(m * 16 + g * 4 + r) * DOUT + w * 64 + r15 * 4] = t2;
        }
}

// ---------------------------------------------------------------------------
// C: combine bf16 partials (permuted layout), softmax denom, leaky-relu,
// L2-normalize, +bias. Wave per row; un-permute on store.
template<int JS>
__global__ __launch_bounds__(256) void k_final(const __bf16* __restrict__ accB,
                                               const float* __restrict__ Sp,
                                               const float* __restrict__ bias,
                                               float* __restrict__ out) {
    int lane = threadIdx.x & 63, wv = threadIdx.x >> 6;
    int row = blockIdx.x * 4 + wv;
    float s = 0.f;
    f32x4 av = (f32x4){0.f, 0.f, 0.f, 0.f};
#pragma unroll
    for (int pp = 0; pp < JS; ++pp) {
        bf16x4 t = *(const bf16x4*)&accB[((size_t)pp * N_NODES + row) * DOUT + lane * 4];
#pragma unroll
        for (int j = 0; j < 4; ++j) av[j] += (float)t[j];
        s += Sp[(size_t)pp * N_NODES + row];
    }
    float inv = 1.0f / fmaxf(s, 1e-30f);
    f32x4 o;
#pragma unroll
    for (int j = 0; j < 4; ++j) {
        float x = av[j] * inv;
        o[j] = fmaxf(x, ALPHA * x);
    }
    float sq = o[0] * o[0] + o[1] * o[1] + o[2] * o[2] + o[3] * o[3];
#pragma unroll
    for (int m = 1; m < 64; m <<= 1) sq += __shfl_xor(sq, m);
    float innrm = 1.0f / fmaxf(sqrtf(sq), 1e-12f);
#pragma unroll
    for (int j = 0; j < 4; ++j) {
        int col = (lane >> 4) * 64 + j * 16 + (lane & 15);
        out[(size_t)row * DOUT + col] = o[j] * innrm + bias[col];
    }
}

// ---------------------------------------------------------------------------
extern "C" void kernel_launch(void* const* d_in, const int* in_sizes, int n_in,
                              void* d_out, int out_size, void* d_ws, size_t ws_size,
                              hipStream_t stream) {
    const float* node   = (const float*)d_in[0];
    const int*   adj    = (const int*)d_in[1];
    const float* weight = (const float*)d_in[2];
    const float* a      = (const float*)d_in[3];
    const float* bias   = (const float*)d_in[4];
    float* out = (float*)d_out;

    const size_t fixed  = 4522240;                 // wB 256K + vB 4M + Q/K 64K + kmax
    const size_t per_js = 32768 + (size_t)N_NODES * DOUT * 2;   // Sp + accB(bf16)
    int js = (ws_size >= fixed + 8 * per_js) ? 8 : 4;

    char* ws = (char*)d_ws;
    bf16x8*   wB      = (bf16x8*)(ws);
    bf16x8*   vB      = (bf16x8*)(ws + 262144);
    float*    Q       = (float*)(ws + 4456448);
    float*    K       = (float*)(ws + 4489216);
    unsigned* kmaxkey = (unsigned*)(ws + 4521984);
    float*    Sp      = (float*)(ws + fixed);
    __bf16*   accB    = (__bf16*)(ws + fixed + (size_t)js * 32768);

    k_repack_w<<<dim3(64),  dim3(256), 0, stream>>>(weight, wB, kmaxkey);
    k_gemm1f  <<<dim3(256), dim3(256), 0, stream>>>(node, wB, a, vB, Q, K, kmaxkey);
    if (js == 8) {
        k_attn<8><<<dim3(128 * 8), dim3(256), 0, stream>>>(adj, vB, Q, K, kmaxkey, accB, Sp);
        k_final<8><<<dim3(2048), dim3(256), 0, stream>>>(accB, Sp, bias, out);
    } else {
        k_attn<4><<<dim3(128 * 4), dim3(256), 0, stream>>>(adj, vB, Q, K, kmaxkey, accB, Sp);
        k_final<4><<<dim3(2048), dim3(256), 0, stream>>>(accB, Sp, bias, out);
    }
}

// Round 2
// 112.962 us; speedup vs baseline: 1.2272x; 1.0811x over previous
//
#include <hip/hip_runtime.h>
#include <hip/hip_bf16.h>

#define N_NODES 8192
#define DIN     512
#define DOUT    256
#define ALPHA   0.2f
#define LOG2E   1.4426950408889634f

typedef __bf16 bf16x8 __attribute__((ext_vector_type(8)));
typedef __bf16 bf16x4 __attribute__((ext_vector_type(4)));
typedef float  f32x4  __attribute__((ext_vector_type(4)));
typedef int    i32x4  __attribute__((ext_vector_type(4)));
typedef unsigned u32x4 __attribute__((ext_vector_type(4)));

// ---------------------------------------------------------------------------
// A0: repack weight f32 [512][256] -> wB bf16 fragment layout. Zeroes kmaxkey.
__global__ __launch_bounds__(256) void k_repack_w(const float* __restrict__ w,
                                                  bf16x8* __restrict__ wB,
                                                  unsigned* __restrict__ kmaxkey) {
    if (blockIdx.x == 0 && threadIdx.x == 0) *kmaxkey = 0u;
    int u = blockIdx.x * 256 + threadIdx.x;   // 16384 units
    int lane = u & 63, t = u >> 6;
    int nt = t & 15, kt = t >> 4;
    int k0 = kt * 32 + (lane >> 4) * 8;
    int col = nt * 16 + (lane & 15);
    bf16x8 r;
#pragma unroll
    for (int i = 0; i < 8; ++i) r[i] = (__bf16)w[(size_t)(k0 + i) * DOUT + col];
    wB[u] = r;
}

// ---------------------------------------------------------------------------
// A1 (fused): v = node @ weight in registers; emits vB fragments (LDS bounce),
// Q/K scalars, global K-max. Grid 256 = 1 blk/CU -> every stall exposed, so:
// node prefetched depth-2, wB fragments depth-1.
__global__ __launch_bounds__(256) void k_gemm1f(const float* __restrict__ node,
                                                const bf16x8* __restrict__ wB,
                                                const float* __restrict__ a,
                                                bf16x8* __restrict__ vBo,
                                                float* __restrict__ Q, float* __restrict__ K,
                                                unsigned* __restrict__ kmaxkey) {
    __shared__ __bf16 vsh[32][260];   // +4 pad
    __shared__ float qksh[32][2];
    int lane = threadIdx.x & 63, w = threadIdx.x >> 6;
    int r15 = lane & 15, g = lane >> 4;
    int nh = w & 1, rh = w >> 1;
    int rowbase = blockIdx.x * 32;
    int myrow = rowbase + rh * 16 + r15;
    const float* np = node + (size_t)myrow * DIN + g * 8;

    f32x4 acc[8];
#pragma unroll
    for (int j = 0; j < 8; ++j) acc[j] = (f32x4){0.f, 0.f, 0.f, 0.f};

    f32x4 c0 = *(const f32x4*)np;
    f32x4 c1 = *(const f32x4*)(np + 4);
    f32x4 c2 = *(const f32x4*)(np + 32);
    f32x4 c3 = *(const f32x4*)(np + 36);
    const bf16x8* wp = wB + (size_t)(nh * 8) * 64 + lane;
    bf16x8 fr0 = wp[0], fr1 = wp[64], fr2 = wp[128], fr3 = wp[192];
    bf16x8 fr4 = wp[256], fr5 = wp[320], fr6 = wp[384], fr7 = wp[448];

    for (int kt = 0; kt < 16; ++kt) {
        f32x4 u0 = c0, u1 = c1;
        c0 = c2; c1 = c3;
        if (kt + 2 < 16) {
            c2 = *(const f32x4*)(np + (kt + 2) * 32);
            c3 = *(const f32x4*)(np + (kt + 2) * 32 + 4);
        }
        bf16x8 f0 = fr0, f1 = fr1, f2 = fr2, f3 = fr3;
        bf16x8 f4 = fr4, f5 = fr5, f6 = fr6, f7 = fr7;
        if (kt + 1 < 16) {
            const bf16x8* wn = wB + ((size_t)(kt + 1) * 16 + nh * 8) * 64 + lane;
            fr0 = wn[0]; fr1 = wn[64]; fr2 = wn[128]; fr3 = wn[192];
            fr4 = wn[256]; fr5 = wn[320]; fr6 = wn[384]; fr7 = wn[448];
        }
        bf16x8 af;
#pragma unroll
        for (int i = 0; i < 4; ++i) { af[i] = (__bf16)u0[i]; af[i + 4] = (__bf16)u1[i]; }
        acc[0] = __builtin_amdgcn_mfma_f32_16x16x32_bf16(af, f0, acc[0], 0, 0, 0);
        acc[1] = __builtin_amdgcn_mfma_f32_16x16x32_bf16(af, f1, acc[1], 0, 0, 0);
        acc[2] = __builtin_amdgcn_mfma_f32_16x16x32_bf16(af, f2, acc[2], 0, 0, 0);
        acc[3] = __builtin_amdgcn_mfma_f32_16x16x32_bf16(af, f3, acc[3], 0, 0, 0);
        acc[4] = __builtin_amdgcn_mfma_f32_16x16x32_bf16(af, f4, acc[4], 0, 0, 0);
        acc[5] = __builtin_amdgcn_mfma_f32_16x16x32_bf16(af, f5, acc[5], 0, 0, 0);
        acc[6] = __builtin_amdgcn_mfma_f32_16x16x32_bf16(af, f6, acc[6], 0, 0, 0);
        acc[7] = __builtin_amdgcn_mfma_f32_16x16x32_bf16(af, f7, acc[7], 0, 0, 0);
    }

    // ---- Q/K partial dots over this wave's 8 nt-columns ----
    float qp0 = 0.f, qp1 = 0.f, qp2 = 0.f, qp3 = 0.f;
    float kp0 = 0.f, kp1 = 0.f, kp2 = 0.f, kp3 = 0.f;
#pragma unroll
    for (int j = 0; j < 8; ++j) {
        int col = (nh * 8 + j) * 16 + r15;
        float a1 = a[col], a2 = a[DOUT + col];
        qp0 += acc[j][0] * a1; qp1 += acc[j][1] * a1;
        qp2 += acc[j][2] * a1; qp3 += acc[j][3] * a1;
        kp0 += acc[j][0] * a2; kp1 += acc[j][1] * a2;
        kp2 += acc[j][2] * a2; kp3 += acc[j][3] * a2;
    }
#pragma unroll
    for (int m = 1; m < 16; m <<= 1) {
        qp0 += __shfl_xor(qp0, m); qp1 += __shfl_xor(qp1, m);
        qp2 += __shfl_xor(qp2, m); qp3 += __shfl_xor(qp3, m);
        kp0 += __shfl_xor(kp0, m); kp1 += __shfl_xor(kp1, m);
        kp2 += __shfl_xor(kp2, m); kp3 += __shfl_xor(kp3, m);
    }

#pragma unroll
    for (int j = 0; j < 8; ++j)
#pragma unroll
        for (int r = 0; r < 4; ++r)
            vsh[rh * 16 + g * 4 + r][(nh * 8 + j) * 16 + r15] = (__bf16)acc[j][r];
    if (nh == 0 && r15 == 0) {
        int rl = rh * 16 + g * 4;
        qksh[rl + 0][0] = qp0; qksh[rl + 1][0] = qp1; qksh[rl + 2][0] = qp2; qksh[rl + 3][0] = qp3;
        qksh[rl + 0][1] = kp0; qksh[rl + 1][1] = kp1; qksh[rl + 2][1] = kp2; qksh[rl + 3][1] = kp3;
    }
    __syncthreads();
    if (nh == 1 && r15 == 0) {
        int rl = rh * 16 + g * 4;
        int rw = rowbase + rl;
        float q0 = qp0 + qksh[rl + 0][0], q1 = qp1 + qksh[rl + 1][0];
        float q2 = qp2 + qksh[rl + 2][0], q3 = qp3 + qksh[rl + 3][0];
        float k0 = kp0 + qksh[rl + 0][1], k1 = kp1 + qksh[rl + 1][1];
        float k2 = kp2 + qksh[rl + 2][1], k3 = kp3 + qksh[rl + 3][1];
        Q[rw + 0] = q0; Q[rw + 1] = q1; Q[rw + 2] = q2; Q[rw + 3] = q3;
        K[rw + 0] = k0; K[rw + 1] = k1; K[rw + 2] = k2; K[rw + 3] = k3;
        float km = fmaxf(fmaxf(k0, k1), fmaxf(k2, k3));
        unsigned bits = __float_as_uint(km);
        unsigned key = (bits & 0x80000000u) ? ~bits : (bits | 0x80000000u);
        atomicMax(kmaxkey, key);
    }
#pragma unroll
    for (int uu = 0; uu < 4; ++uu) {
        int nt = w * 4 + uu;
        bf16x8 t;
#pragma unroll
        for (int i = 0; i < 8; ++i) t[i] = vsh[g * 8 + i][nt * 16 + r15];
        vBo[((size_t)blockIdx.x * 16 + nt) * 64 + lane] = t;
    }
}

// ---------------------------------------------------------------------------
// B: fused masked-softmax-numerator GEMM with adj streaming pipelined into
// the MFMA loop. Round-2 change: WAVE-COALESCED adj loads. Old pattern put
// 64 lanes on 64 distinct 64B sectors at 128B stride (16B consumed each) ->
// 4x L2 transactions, ~55% effective stream BW. New mapping: instr q, wave w:
// lanes 0-31 read a contiguous 512B row segment, lanes 32-63 the next row's.
// Bit-pack via 4 __ballot per instr (ballot_e bit k <-> col 4k+e); lanes 0/32
// store the row's 4 mask dwords. Consumer decodes U[i&3] >> (s*8+g*2+(i>>2)).
// Loads for group G+3 issued at iter G, packed at G+2, read at G+3 -> the
// per-BODYM lgkmcnt(0)+s_barrier fences Ms stores with 2 barriers to spare.
template<int JS>
__global__ __launch_bounds__(256, 2) void k_attn(const int* __restrict__ adj,
                                                 const bf16x8* __restrict__ vBg,
                                                 const float* __restrict__ Q,
                                                 const float* __restrict__ K,
                                                 const unsigned* __restrict__ kmaxkey,
                                                 __bf16* __restrict__ accB,
                                                 float* __restrict__ Sp) {
    constexpr int JR   = N_NODES / JS;
    constexpr int BIT  = JR / 32;          // mask dwords per row (32 for JS=8)
    constexpr int NG   = BIT / 4;          // 4-BODYM groups (8 for JS=8)
    constexpr int MSTR = BIT + 4;          // pad: row stride 144B, 16B-aligned
    __shared__ float    Ks[JR];
    __shared__ unsigned Ms[64][MSTR];
    __shared__ bf16x8   pT[2][4][64];

    int bid = blockIdx.x;
    int rb = bid / JS, p = bid % JS;       // p == XCD id (grid % 8 == 0)
    int lane = threadIdx.x & 63, w = threadIdx.x >> 6;
    int r15 = lane & 15, g = lane >> 4;
    int rowbase = rb * 64;
    int prow = rowbase + w * 16 + r15;
    int j0 = p * JR;

    for (int s = threadIdx.x * 4; s < JR; s += 1024)
        *(f32x4*)&Ks[s] = *(const f32x4*)&K[j0 + s];

    // coalesced adj mapping: instr q covers rows q*8 + w*2 + (lane>>5);
    // lane's 16B at column ints (lane&31)*4 within the group's 128-int span.
    const int hrow = w * 2 + (lane >> 5);          // 0..7
    const int* abase = adj + (size_t)(rowbase + hrow) * N_NODES + j0 + (lane & 31) * 4;

#define ISSUE8(L, GG) { _Pragma("unroll")                                        \
    for (int q = 0; q < 8; ++q)                                                  \
        L[q] = *(const i32x4*)(abase + (size_t)(q * 8) * N_NODES + (GG) * 128); }

#define PACKB(L, GG) { _Pragma("unroll") for (int q = 0; q < 8; ++q) {           \
    unsigned long long b0_ = __ballot(L[q][0] != 0);                             \
    unsigned long long b1_ = __ballot(L[q][1] != 0);                             \
    unsigned long long b2_ = __ballot(L[q][2] != 0);                             \
    unsigned long long b3_ = __ballot(L[q][3] != 0);                             \
    if ((lane & 31) == 0) {                                                      \
        int hi_ = lane >> 5;                                                     \
        u32x4 u_;                                                                \
        u_[0] = hi_ ? (unsigned)(b0_ >> 32) : (unsigned)b0_;                     \
        u_[1] = hi_ ? (unsigned)(b1_ >> 32) : (unsigned)b1_;                     \
        u_[2] = hi_ ? (unsigned)(b2_ >> 32) : (unsigned)b2_;                     \
        u_[3] = hi_ ? (unsigned)(b3_ >> 32) : (unsigned)b3_;                     \
        *(u32x4*)&Ms[q * 8 + hrow][(GG) * 4] = u_;                               \
    } } }

    // prologue: pack groups 0,1; leave group-2 loads in flight
    i32x4 La[8];
    {
        i32x4 Lb[8];
        ISSUE8(La, 0)
        ISSUE8(Lb, 1)
        PACKB(La, 0)
        PACKB(Lb, 1)
    }
    ISSUE8(La, 2)

    float qi = Q[prow];
    unsigned kk = *kmaxkey;
    unsigned kb = (kk & 0x80000000u) ? (kk ^ 0x80000000u) : ~kk;
    float kmax = __uint_as_float(kb);
    float t0 = qi + kmax;
    float c2 = fmaxf(t0, ALPHA * t0) * LOG2E;
    // lrelu+shift folded: exp2(max(kj*L + A1, kj*(aL) + A2))
    float qiL = qi * LOG2E;
    float A1 = qiL - c2;
    float A2 = ALPHA * qiL - c2;

    const bf16x8* vbp = vBg + ((size_t)(p * BIT) * 16 + w * 4) * 64 + lane;

    f32x4 acc[4][4];
#pragma unroll
    for (int m = 0; m < 4; ++m)
#pragma unroll
        for (int n = 0; n < 4; ++n) acc[m][n] = (f32x4){0.f, 0.f, 0.f, 0.f};
    float sl = 0.f;

    // Ks + Ms groups 0,1 ready. Raw barrier (NOT __syncthreads: that would
    // vmcnt(0)-drain the in-flight group-2 adj loads).
    asm volatile("s_waitcnt lgkmcnt(0)" ::: "memory");
    __builtin_amdgcn_s_barrier();
    asm volatile("" ::: "memory");

    // prefetch: mask dwords (group 0) for this lane's P-row; vB depth-2
    u32x4 Uc = *(const u32x4*)&Ms[w * 16 + r15][0];
    bf16x8 vS0 = vbp[0],    vS1 = vbp[64],   vS2 = vbp[128],  vS3 = vbp[192];
    bf16x8 vT0 = vbp[1024], vT1 = vbp[1088], vT2 = vbp[1152], vT3 = vbp[1216];

#define BODYM(UU, S, V0, V1, V2, V3, BUF, itv)                                  \
    {                                                                           \
        bf16x8 b0 = V0, b1 = V1, b2 = V2, b3 = V3;                              \
        if ((itv) + 2 < BIT) {                                                  \
            V0 = vbp[((itv) + 2) * 1024];       V1 = vbp[((itv) + 2) * 1024 + 64];  \
            V2 = vbp[((itv) + 2) * 1024 + 128]; V3 = vbp[((itv) + 2) * 1024 + 192]; \
        }                                                                       \
        f32x4 q0 = *(const f32x4*)&Ks[(itv) * 32 + g * 8];                      \
        f32x4 q1 = *(const f32x4*)&Ks[(itv) * 32 + g * 8 + 4];                  \
        unsigned bsh = (S) * 8 + g * 2;                                         \
        unsigned m0 = UU[0] >> bsh, m1 = UU[1] >> bsh;                          \
        unsigned m2 = UU[2] >> bsh, m3 = UU[3] >> bsh;                          \
        bf16x8 af;                                                              \
        _Pragma("unroll")                                                       \
        for (int i = 0; i < 8; ++i) {                                           \
            float kj = (i < 4) ? q0[i] : q1[i - 4];                             \
            float f1 = __builtin_fmaf(kj, LOG2E, A1);                           \
            float f2 = __builtin_fmaf(kj, ALPHA * LOG2E, A2);                   \
            float pv = __builtin_amdgcn_exp2f(fmaxf(f1, f2));                   \
            unsigned mm_ = (i & 3) == 0 ? m0 : ((i & 3) == 1 ? m1 : ((i & 3) == 2 ? m2 : m3)); \
            pv = (mm_ & (1u << (i >> 2))) ? pv : 0.f;                           \
            sl += pv;                                                           \
            af[i] = (__bf16)pv;                                                 \
        }                                                                       \
        pT[BUF][w][lane] = af;                                                  \
        asm volatile("s_waitcnt lgkmcnt(0)" ::: "memory");                      \
        __builtin_amdgcn_s_barrier();                                           \
        asm volatile("" ::: "memory");                                         \
        bf16x8 pa0 = pT[BUF][0][lane], pa1 = pT[BUF][1][lane];                  \
        bf16x8 pa2 = pT[BUF][2][lane], pa3 = pT[BUF][3][lane];                  \
        acc[0][0] = __builtin_amdgcn_mfma_f32_16x16x32_bf16(pa0, b0, acc[0][0], 0, 0, 0); \
        acc[0][1] = __builtin_amdgcn_mfma_f32_16x16x32_bf16(pa0, b1, acc[0][1], 0, 0, 0); \
        acc[0][2] = __builtin_amdgcn_mfma_f32_16x16x32_bf16(pa0, b2, acc[0][2], 0, 0, 0); \
        acc[0][3] = __builtin_amdgcn_mfma_f32_16x16x32_bf16(pa0, b3, acc[0][3], 0, 0, 0); \
        acc[1][0] = __builtin_amdgcn_mfma_f32_16x16x32_bf16(pa1, b0, acc[1][0], 0, 0, 0); \
        acc[1][1] = __builtin_amdgcn_mfma_f32_16x16x32_bf16(pa1, b1, acc[1][1], 0, 0, 0); \
        acc[1][2] = __builtin_amdgcn_mfma_f32_16x16x32_bf16(pa1, b2, acc[1][2], 0, 0, 0); \
        acc[1][3] = __builtin_amdgcn_mfma_f32_16x16x32_bf16(pa1, b3, acc[1][3], 0, 0, 0); \
        acc[2][0] = __builtin_amdgcn_mfma_f32_16x16x32_bf16(pa2, b0, acc[2][0], 0, 0, 0); \
        acc[2][1] = __builtin_amdgcn_mfma_f32_16x16x32_bf16(pa2, b1, acc[2][1], 0, 0, 0); \
        acc[2][2] = __builtin_amdgcn_mfma_f32_16x16x32_bf16(pa2, b2, acc[2][2], 0, 0, 0); \
        acc[2][3] = __builtin_amdgcn_mfma_f32_16x16x32_bf16(pa2, b3, acc[2][3], 0, 0, 0); \
        acc[3][0] = __builtin_amdgcn_mfma_f32_16x16x32_bf16(pa3, b0, acc[3][0], 0, 0, 0); \
        acc[3][1] = __builtin_amdgcn_mfma_f32_16x16x32_bf16(pa3, b1, acc[3][1], 0, 0, 0); \
        acc[3][2] = __builtin_amdgcn_mfma_f32_16x16x32_bf16(pa3, b2, acc[3][2], 0, 0, 0); \
        acc[3][3] = __builtin_amdgcn_mfma_f32_16x16x32_bf16(pa3, b3, acc[3][3], 0, 0, 0); \
    }

    for (int G = 0; G < NG; ++G) {
        const int it4 = G * 4;
        u32x4 Un = Uc;
        if (G + 1 < NG) Un = *(const u32x4*)&Ms[w * 16 + r15][it4 + 4];
        BODYM(Uc, 0, vS0, vS1, vS2, vS3, 0, it4 + 0)
        BODYM(Uc, 1, vT0, vT1, vT2, vT3, 1, it4 + 1)
        // staged adj pack: ballots+store for group G+2 (loads issued at G-1),
        // then issue loads for group G+3. The two following BODYM barriers
        // fence the Ms store before iter G+1 reads it via Un.
        if (G + 2 < NG) {
            PACKB(La, G + 2)
            if (G + 3 < NG) ISSUE8(La, G + 3)
        }
        BODYM(Uc, 2, vS0, vS1, vS2, vS3, 0, it4 + 2)
        BODYM(Uc, 3, vT0, vT1, vT2, vT3, 1, it4 + 3)
        Uc = Un;
    }
#undef BODYM
#undef ISSUE8
#undef PACKB

    sl += __shfl_xor(sl, 16);
    sl += __shfl_xor(sl, 32);
    if (g == 0) Sp[(size_t)p * N_NODES + prow] = sl;

    __bf16* apb = accB + ((size_t)p * N_NODES + rowbase) * DOUT;
#pragma unroll
    for (int m = 0; m < 4; ++m)
#pragma unroll
        for (int r = 0; r < 4; ++r) {
            bf16x4 t2;
#pragma unroll
            for (int n = 0; n < 4; ++n) t2[n] = (__bf16)acc[m][n][r];
            *(bf16x4*)&apb[(size_t)(m * 16 + g * 4 + r) * DOUT + w * 64 + r15 * 4] = t2;
        }
}

// ---------------------------------------------------------------------------
// C: combine bf16 partials (permuted layout), softmax denom, leaky-relu,
// L2-normalize, +bias. Wave per row; un-permute on store.
template<int JS>
__global__ __launch_bounds__(256) void k_final(const __bf16* __restrict__ accB,
                                               const float* __restrict__ Sp,
                                               const float* __restrict__ bias,
                                               float* __restrict__ out) {
    int lane = threadIdx.x & 63, wv = threadIdx.x >> 6;
    int row = blockIdx.x * 4 + wv;
    float s = 0.f;
    f32x4 av = (f32x4){0.f, 0.f, 0.f, 0.f};
#pragma unroll
    for (int pp = 0; pp < JS; ++pp) {
        bf16x4 t = *(const bf16x4*)&accB[((size_t)pp * N_NODES + row) * DOUT + lane * 4];
#pragma unroll
        for (int j = 0; j < 4; ++j) av[j] += (float)t[j];
        s += Sp[(size_t)pp * N_NODES + row];
    }
    float inv = 1.0f / fmaxf(s, 1e-30f);
    f32x4 o;
#pragma unroll
    for (int j = 0; j < 4; ++j) {
        float x = av[j] * inv;
        o[j] = fmaxf(x, ALPHA * x);
    }
    float sq = o[0] * o[0] + o[1] * o[1] + o[2] * o[2] + o[3] * o[3];
#pragma unroll
    for (int m = 1; m < 64; m <<= 1) sq += __shfl_xor(sq, m);
    float innrm = 1.0f / fmaxf(sqrtf(sq), 1e-12f);
#pragma unroll
    for (int j = 0; j < 4; ++j) {
        int col = (lane >> 4) * 64 + j * 16 + (lane & 15);
        out[(size_t)row * DOUT + col] = o[j] * innrm + bias[col];
    }
}

// ---------------------------------------------------------------------------
extern "C" void kernel_launch(void* const* d_in, const int* in_sizes, int n_in,
                              void* d_out, int out_size, void* d_ws, size_t ws_size,
                              hipStream_t stream) {
    const float* node   = (const float*)d_in[0];
    const int*   adj    = (const int*)d_in[1];
    const float* weight = (const float*)d_in[2];
    const float* a      = (const float*)d_in[3];
    const float* bias   = (const float*)d_in[4];
    float* out = (float*)d_out;

    const size_t fixed  = 4522240;                 // wB 256K + vB 4M + Q/K 64K + kmax
    const size_t per_js = 32768 + (size_t)N_NODES * DOUT * 2;   // Sp + accB(bf16)
    int js = (ws_size >= fixed + 8 * per_js) ? 8 : 4;

    char* ws = (char*)d_ws;
    bf16x8*   wB      = (bf16x8*)(ws);
    bf16x8*   vB      = (bf16x8*)(ws + 262144);
    float*    Q       = (float*)(ws + 4456448);
    float*    K       = (float*)(ws + 4489216);
    unsigned* kmaxkey = (unsigned*)(ws + 4521984);
    float*    Sp      = (float*)(ws + fixed);
    __bf16*   accB    = (__bf16*)(ws + fixed + (size_t)js * 32768);

    k_repack_w<<<dim3(64),  dim3(256), 0, stream>>>(weight, wB, kmaxkey);
    k_gemm1f  <<<dim3(256), dim3(256), 0, stream>>>(node, wB, a, vB, Q, K, kmaxkey);
    if (js == 8) {
        k_attn<8><<<dim3(128 * 8), dim3(256), 0, stream>>>(adj, vB, Q, K, kmaxkey, accB, Sp);
        k_final<8><<<dim3(2048), dim3(256), 0, stream>>>(accB, Sp, bias, out);
    } else {
        k_attn<4><<<dim3(128 * 4), dim3(256), 0, stream>>>(adj, vB, Q, K, kmaxkey, accB, Sp);
        k_final<4><<<dim3(2048), dim3(256), 0, stream>>>(accB, Sp, bias, out);
    }
}

// Round 3
// 111.130 us; speedup vs baseline: 1.2474x; 1.0165x over previous
//
#include <hip/hip_runtime.h>
#include <hip/hip_bf16.h>

#define N_NODES 8192
#define DIN     512
#define DOUT    256
#define ALPHA   0.2f
#define LOG2E   1.4426950408889634f

typedef __bf16 bf16x8 __attribute__((ext_vector_type(8)));
typedef __bf16 bf16x4 __attribute__((ext_vector_type(4)));
typedef float  f32x4  __attribute__((ext_vector_type(4)));
typedef int    i32x4  __attribute__((ext_vector_type(4)));
typedef unsigned u32x4 __attribute__((ext_vector_type(4)));

// ---------------------------------------------------------------------------
// A0: repack weight f32 [512][256] -> wB bf16 fragment layout. Zeroes kmaxkey.
__global__ __launch_bounds__(256) void k_repack_w(const float* __restrict__ w,
                                                  bf16x8* __restrict__ wB,
                                                  unsigned* __restrict__ kmaxkey) {
    if (blockIdx.x == 0 && threadIdx.x == 0) *kmaxkey = 0u;
    int u = blockIdx.x * 256 + threadIdx.x;   // 16384 units
    int lane = u & 63, t = u >> 6;
    int nt = t & 15, kt = t >> 4;
    int k0 = kt * 32 + (lane >> 4) * 8;
    int col = nt * 16 + (lane & 15);
    bf16x8 r;
#pragma unroll
    for (int i = 0; i < 8; ++i) r[i] = (__bf16)w[(size_t)(k0 + i) * DOUT + col];
    wB[u] = r;
}

// ---------------------------------------------------------------------------
// A1 (fused): v = node @ weight in registers; emits vB fragments (LDS bounce),
// Q/K scalars, global K-max. Grid 256 = 1 blk/CU -> every stall exposed, so:
// node prefetched depth-2, wB fragments depth-1.
__global__ __launch_bounds__(256) void k_gemm1f(const float* __restrict__ node,
                                                const bf16x8* __restrict__ wB,
                                                const float* __restrict__ a,
                                                bf16x8* __restrict__ vBo,
                                                float* __restrict__ Q, float* __restrict__ K,
                                                unsigned* __restrict__ kmaxkey) {
    __shared__ __bf16 vsh[32][260];   // +4 pad
    __shared__ float qksh[32][2];
    int lane = threadIdx.x & 63, w = threadIdx.x >> 6;
    int r15 = lane & 15, g = lane >> 4;
    int nh = w & 1, rh = w >> 1;
    int rowbase = blockIdx.x * 32;
    int myrow = rowbase + rh * 16 + r15;
    const float* np = node + (size_t)myrow * DIN + g * 8;

    f32x4 acc[8];
#pragma unroll
    for (int j = 0; j < 8; ++j) acc[j] = (f32x4){0.f, 0.f, 0.f, 0.f};

    f32x4 c0 = *(const f32x4*)np;
    f32x4 c1 = *(const f32x4*)(np + 4);
    f32x4 c2 = *(const f32x4*)(np + 32);
    f32x4 c3 = *(const f32x4*)(np + 36);
    const bf16x8* wp = wB + (size_t)(nh * 8) * 64 + lane;
    bf16x8 fr0 = wp[0], fr1 = wp[64], fr2 = wp[128], fr3 = wp[192];
    bf16x8 fr4 = wp[256], fr5 = wp[320], fr6 = wp[384], fr7 = wp[448];

    for (int kt = 0; kt < 16; ++kt) {
        f32x4 u0 = c0, u1 = c1;
        c0 = c2; c1 = c3;
        if (kt + 2 < 16) {
            c2 = *(const f32x4*)(np + (kt + 2) * 32);
            c3 = *(const f32x4*)(np + (kt + 2) * 32 + 4);
        }
        bf16x8 f0 = fr0, f1 = fr1, f2 = fr2, f3 = fr3;
        bf16x8 f4 = fr4, f5 = fr5, f6 = fr6, f7 = fr7;
        if (kt + 1 < 16) {
            const bf16x8* wn = wB + ((size_t)(kt + 1) * 16 + nh * 8) * 64 + lane;
            fr0 = wn[0]; fr1 = wn[64]; fr2 = wn[128]; fr3 = wn[192];
            fr4 = wn[256]; fr5 = wn[320]; fr6 = wn[384]; fr7 = wn[448];
        }
        bf16x8 af;
#pragma unroll
        for (int i = 0; i < 4; ++i) { af[i] = (__bf16)u0[i]; af[i + 4] = (__bf16)u1[i]; }
        acc[0] = __builtin_amdgcn_mfma_f32_16x16x32_bf16(af, f0, acc[0], 0, 0, 0);
        acc[1] = __builtin_amdgcn_mfma_f32_16x16x32_bf16(af, f1, acc[1], 0, 0, 0);
        acc[2] = __builtin_amdgcn_mfma_f32_16x16x32_bf16(af, f2, acc[2], 0, 0, 0);
        acc[3] = __builtin_amdgcn_mfma_f32_16x16x32_bf16(af, f3, acc[3], 0, 0, 0);
        acc[4] = __builtin_amdgcn_mfma_f32_16x16x32_bf16(af, f4, acc[4], 0, 0, 0);
        acc[5] = __builtin_amdgcn_mfma_f32_16x16x32_bf16(af, f5, acc[5], 0, 0, 0);
        acc[6] = __builtin_amdgcn_mfma_f32_16x16x32_bf16(af, f6, acc[6], 0, 0, 0);
        acc[7] = __builtin_amdgcn_mfma_f32_16x16x32_bf16(af, f7, acc[7], 0, 0, 0);
    }

    // ---- Q/K partial dots over this wave's 8 nt-columns ----
    float qp0 = 0.f, qp1 = 0.f, qp2 = 0.f, qp3 = 0.f;
    float kp0 = 0.f, kp1 = 0.f, kp2 = 0.f, kp3 = 0.f;
#pragma unroll
    for (int j = 0; j < 8; ++j) {
        int col = (nh * 8 + j) * 16 + r15;
        float a1 = a[col], a2 = a[DOUT + col];
        qp0 += acc[j][0] * a1; qp1 += acc[j][1] * a1;
        qp2 += acc[j][2] * a1; qp3 += acc[j][3] * a1;
        kp0 += acc[j][0] * a2; kp1 += acc[j][1] * a2;
        kp2 += acc[j][2] * a2; kp3 += acc[j][3] * a2;
    }
#pragma unroll
    for (int m = 1; m < 16; m <<= 1) {
        qp0 += __shfl_xor(qp0, m); qp1 += __shfl_xor(qp1, m);
        qp2 += __shfl_xor(qp2, m); qp3 += __shfl_xor(qp3, m);
        kp0 += __shfl_xor(kp0, m); kp1 += __shfl_xor(kp1, m);
        kp2 += __shfl_xor(kp2, m); kp3 += __shfl_xor(kp3, m);
    }

#pragma unroll
    for (int j = 0; j < 8; ++j)
#pragma unroll
        for (int r = 0; r < 4; ++r)
            vsh[rh * 16 + g * 4 + r][(nh * 8 + j) * 16 + r15] = (__bf16)acc[j][r];
    if (nh == 0 && r15 == 0) {
        int rl = rh * 16 + g * 4;
        qksh[rl + 0][0] = qp0; qksh[rl + 1][0] = qp1; qksh[rl + 2][0] = qp2; qksh[rl + 3][0] = qp3;
        qksh[rl + 0][1] = kp0; qksh[rl + 1][1] = kp1; qksh[rl + 2][1] = kp2; qksh[rl + 3][1] = kp3;
    }
    __syncthreads();
    if (nh == 1 && r15 == 0) {
        int rl = rh * 16 + g * 4;
        int rw = rowbase + rl;
        float q0 = qp0 + qksh[rl + 0][0], q1 = qp1 + qksh[rl + 1][0];
        float q2 = qp2 + qksh[rl + 2][0], q3 = qp3 + qksh[rl + 3][0];
        float k0 = kp0 + qksh[rl + 0][1], k1 = kp1 + qksh[rl + 1][1];
        float k2 = kp2 + qksh[rl + 2][1], k3 = kp3 + qksh[rl + 3][1];
        Q[rw + 0] = q0; Q[rw + 1] = q1; Q[rw + 2] = q2; Q[rw + 3] = q3;
        K[rw + 0] = k0; K[rw + 1] = k1; K[rw + 2] = k2; K[rw + 3] = k3;
        float km = fmaxf(fmaxf(k0, k1), fmaxf(k2, k3));
        unsigned bits = __float_as_uint(km);
        unsigned key = (bits & 0x80000000u) ? ~bits : (bits | 0x80000000u);
        atomicMax(kmaxkey, key);
    }
#pragma unroll
    for (int uu = 0; uu < 4; ++uu) {
        int nt = w * 4 + uu;
        bf16x8 t;
#pragma unroll
        for (int i = 0; i < 8; ++i) t[i] = vsh[g * 8 + i][nt * 16 + r15];
        vBo[((size_t)blockIdx.x * 16 + nt) * 64 + lane] = t;
    }
}

// ---------------------------------------------------------------------------
// B: fused masked-softmax-numerator GEMM. Round-3 change: ONE-STEP SOFTWARE
// PIPELINE of the P fragment. Old: compute exp(t) -> store pT -> barrier ->
// MFMA(t): the barrier fenced freshly-computed data, so exp and MFMA phases
// serialized block-wide, 32x, and HBM idled during both. New: iteration t
// stores af(t) (computed LAST iteration), barriers (pure sync, data is one
// full step old), then computes af(t+1) BETWEEN the pa ds_reads and the
// MFMAs -> exp VALU chain runs in the shadow of LDS latency + MFMA pipe.
// Mask-word plumbing shifts one step: sub-step S consumes word S+1 (Un[0]
// at S=3; Un loaded a group early, 2 barriers of slack preserved).
// Adj streaming (coalesced + ballot-pack, G+3 issue / G+2 pack) unchanged.
template<int JS>
__global__ __launch_bounds__(256, 2) void k_attn(const int* __restrict__ adj,
                                                 const bf16x8* __restrict__ vBg,
                                                 const float* __restrict__ Q,
                                                 const float* __restrict__ K,
                                                 const unsigned* __restrict__ kmaxkey,
                                                 __bf16* __restrict__ accB,
                                                 float* __restrict__ Sp) {
    constexpr int JR   = N_NODES / JS;
    constexpr int BIT  = JR / 32;          // k-steps (32 for JS=8)
    constexpr int NG   = BIT / 4;          // 4-step groups (8 for JS=8)
    constexpr int MSTR = BIT + 4;          // pad: row stride 144B, 16B-aligned
    __shared__ float    Ks[JR];
    __shared__ unsigned Ms[64][MSTR];
    __shared__ bf16x8   pT[2][4][64];

    int bid = blockIdx.x;
    int rb = bid / JS, p = bid % JS;       // p == XCD id (grid % 8 == 0)
    int lane = threadIdx.x & 63, w = threadIdx.x >> 6;
    int r15 = lane & 15, g = lane >> 4;
    int rowbase = rb * 64;
    int prow = rowbase + w * 16 + r15;
    int j0 = p * JR;

    for (int s = threadIdx.x * 4; s < JR; s += 1024)
        *(f32x4*)&Ks[s] = *(const f32x4*)&K[j0 + s];

    // coalesced adj mapping: instr q covers rows q*8 + w*2 + (lane>>5);
    // lane's 16B at column ints (lane&31)*4 within the group's 128-int span.
    const int hrow = w * 2 + (lane >> 5);          // 0..7
    const int* abase = adj + (size_t)(rowbase + hrow) * N_NODES + j0 + (lane & 31) * 4;

#define ISSUE8(L, GG) { _Pragma("unroll")                                        \
    for (int q = 0; q < 8; ++q)                                                  \
        L[q] = *(const i32x4*)(abase + (size_t)(q * 8) * N_NODES + (GG) * 128); }

#define PACKB(L, GG) { _Pragma("unroll") for (int q = 0; q < 8; ++q) {           \
    unsigned long long b0_ = __ballot(L[q][0] != 0);                             \
    unsigned long long b1_ = __ballot(L[q][1] != 0);                             \
    unsigned long long b2_ = __ballot(L[q][2] != 0);                             \
    unsigned long long b3_ = __ballot(L[q][3] != 0);                             \
    if ((lane & 31) == 0) {                                                      \
        int hi_ = lane >> 5;                                                     \
        u32x4 u_;                                                                \
        u_[0] = hi_ ? (unsigned)(b0_ >> 32) : (unsigned)b0_;                     \
        u_[1] = hi_ ? (unsigned)(b1_ >> 32) : (unsigned)b1_;                     \
        u_[2] = hi_ ? (unsigned)(b2_ >> 32) : (unsigned)b2_;                     \
        u_[3] = hi_ ? (unsigned)(b3_ >> 32) : (unsigned)b3_;                     \
        *(u32x4*)&Ms[q * 8 + hrow][(GG) * 4] = u_;                               \
    } } }

    // prologue: pack groups 0,1; leave group-2 loads in flight
    i32x4 La[8];
    {
        i32x4 Lb[8];
        ISSUE8(La, 0)
        ISSUE8(Lb, 1)
        PACKB(La, 0)
        PACKB(Lb, 1)
    }
    ISSUE8(La, 2)

    float qi = Q[prow];
    unsigned kk = *kmaxkey;
    unsigned kb = (kk & 0x80000000u) ? (kk ^ 0x80000000u) : ~kk;
    float kmax = __uint_as_float(kb);
    float t0 = qi + kmax;
    float c2 = fmaxf(t0, ALPHA * t0) * LOG2E;
    // lrelu+shift folded: exp2(max(kj*L + A1, kj*(aL) + A2))
    float qiL = qi * LOG2E;
    float A1 = qiL - c2;
    float A2 = ALPHA * qiL - c2;

    const bf16x8* vbp = vBg + ((size_t)(p * BIT) * 16 + w * 4) * 64 + lane;

    f32x4 acc[4][4];
#pragma unroll
    for (int m = 0; m < 4; ++m)
#pragma unroll
        for (int n = 0; n < 4; ++n) acc[m][n] = (f32x4){0.f, 0.f, 0.f, 0.f};
    float sl = 0.f;

    // Ks + Ms groups 0,1 ready. Raw barrier (NOT __syncthreads: that would
    // vmcnt(0)-drain the in-flight group-2 adj loads).
    asm volatile("s_waitcnt lgkmcnt(0)" ::: "memory");
    __builtin_amdgcn_s_barrier();
    asm volatile("" ::: "memory");

    // prefetch: mask dwords (group 0) for this lane's P-row; vB depth-2
    u32x4 Uc = *(const u32x4*)&Ms[w * 16 + r15][0];
    bf16x8 vS0 = vbp[0],    vS1 = vbp[64],   vS2 = vbp[128],  vS3 = vbp[192];
    bf16x8 vT0 = vbp[1024], vT1 = vbp[1088], vT2 = vbp[1152], vT3 = vbp[1216];

    // EXPBLK(WN4, SN, kstep): compute af for k-step `kstep` into afc
#define EXPBLK(WN4, SN, kstep)                                                  \
    {                                                                           \
        f32x4 q0 = *(const f32x4*)&Ks[(kstep) * 32 + g * 8];                    \
        f32x4 q1 = *(const f32x4*)&Ks[(kstep) * 32 + g * 8 + 4];                \
        unsigned bsh = (SN) * 8 + g * 2;                                        \
        unsigned m0 = (WN4)[0] >> bsh, m1 = (WN4)[1] >> bsh;                    \
        unsigned m2 = (WN4)[2] >> bsh, m3 = (WN4)[3] >> bsh;                    \
        _Pragma("unroll")                                                       \
        for (int i = 0; i < 8; ++i) {                                           \
            float kj = (i < 4) ? q0[i] : q1[i - 4];                             \
            float f1 = __builtin_fmaf(kj, LOG2E, A1);                           \
            float f2 = __builtin_fmaf(kj, ALPHA * LOG2E, A2);                   \
            float pv = __builtin_amdgcn_exp2f(fmaxf(f1, f2));                   \
            unsigned mm_ = (i & 3) == 0 ? m0 : ((i & 3) == 1 ? m1 : ((i & 3) == 2 ? m2 : m3)); \
            pv = (mm_ & (1u << (i >> 2))) ? pv : 0.f;                           \
            sl += pv;                                                           \
            afc[i] = (__bf16)pv;                                                \
        }                                                                       \
    }

    // prologue for the P pipeline: afc = fragment of k-step 0
    bf16x8 afc;
    EXPBLK(Uc, 0, 0)

#define BODYM(WN4, SN, V0, V1, V2, V3, BUF, itv)                                \
    {                                                                           \
        bf16x8 b0 = V0, b1 = V1, b2 = V2, b3 = V3;                              \
        if ((itv) + 2 < BIT) {                                                  \
            V0 = vbp[((itv) + 2) * 1024];       V1 = vbp[((itv) + 2) * 1024 + 64];  \
            V2 = vbp[((itv) + 2) * 1024 + 128]; V3 = vbp[((itv) + 2) * 1024 + 192]; \
        }                                                                       \
        pT[BUF][w][lane] = afc;                                                 \
        asm volatile("s_waitcnt lgkmcnt(0)" ::: "memory");                      \
        __builtin_amdgcn_s_barrier();                                           \
        asm volatile("" ::: "memory");                                         \
        bf16x8 pa0 = pT[BUF][0][lane], pa1 = pT[BUF][1][lane];                  \
        bf16x8 pa2 = pT[BUF][2][lane], pa3 = pT[BUF][3][lane];                  \
        if ((itv) + 1 < BIT) EXPBLK(WN4, SN, (itv) + 1)                         \
        acc[0][0] = __builtin_amdgcn_mfma_f32_16x16x32_bf16(pa0, b0, acc[0][0], 0, 0, 0); \
        acc[0][1] = __builtin_amdgcn_mfma_f32_16x16x32_bf16(pa0, b1, acc[0][1], 0, 0, 0); \
        acc[0][2] = __builtin_amdgcn_mfma_f32_16x16x32_bf16(pa0, b2, acc[0][2], 0, 0, 0); \
        acc[0][3] = __builtin_amdgcn_mfma_f32_16x16x32_bf16(pa0, b3, acc[0][3], 0, 0, 0); \
        acc[1][0] = __builtin_amdgcn_mfma_f32_16x16x32_bf16(pa1, b0, acc[1][0], 0, 0, 0); \
        acc[1][1] = __builtin_amdgcn_mfma_f32_16x16x32_bf16(pa1, b1, acc[1][1], 0, 0, 0); \
        acc[1][2] = __builtin_amdgcn_mfma_f32_16x16x32_bf16(pa1, b2, acc[1][2], 0, 0, 0); \
        acc[1][3] = __builtin_amdgcn_mfma_f32_16x16x32_bf16(pa1, b3, acc[1][3], 0, 0, 0); \
        acc[2][0] = __builtin_amdgcn_mfma_f32_16x16x32_bf16(pa2, b0, acc[2][0], 0, 0, 0); \
        acc[2][1] = __builtin_amdgcn_mfma_f32_16x16x32_bf16(pa2, b1, acc[2][1], 0, 0, 0); \
        acc[2][2] = __builtin_amdgcn_mfma_f32_16x16x32_bf16(pa2, b2, acc[2][2], 0, 0, 0); \
        acc[2][3] = __builtin_amdgcn_mfma_f32_16x16x32_bf16(pa2, b3, acc[2][3], 0, 0, 0); \
        acc[3][0] = __builtin_amdgcn_mfma_f32_16x16x32_bf16(pa3, b0, acc[3][0], 0, 0, 0); \
        acc[3][1] = __builtin_amdgcn_mfma_f32_16x16x32_bf16(pa3, b1, acc[3][1], 0, 0, 0); \
        acc[3][2] = __builtin_amdgcn_mfma_f32_16x16x32_bf16(pa3, b2, acc[3][2], 0, 0, 0); \
        acc[3][3] = __builtin_amdgcn_mfma_f32_16x16x32_bf16(pa3, b3, acc[3][3], 0, 0, 0); \
    }

    for (int G = 0; G < NG; ++G) {
        const int it4 = G * 4;
        u32x4 Un = Uc;
        if (G + 1 < NG) Un = *(const u32x4*)&Ms[w * 16 + r15][it4 + 4];
        BODYM(Uc, 1, vS0, vS1, vS2, vS3, 0, it4 + 0)
        BODYM(Uc, 2, vT0, vT1, vT2, vT3, 1, it4 + 1)
        // staged adj pack: ballots+store for group G+2 (loads issued at G-1),
        // then issue loads for group G+3. The two following BODYM barriers
        // fence the Ms store before iter G+1 reads it via Un.
        if (G + 2 < NG) {
            PACKB(La, G + 2)
            if (G + 3 < NG) ISSUE8(La, G + 3)
        }
        BODYM(Uc, 3, vS0, vS1, vS2, vS3, 0, it4 + 2)
        BODYM(Un, 0, vT0, vT1, vT2, vT3, 1, it4 + 3)
        Uc = Un;
    }
#undef BODYM
#undef EXPBLK
#undef ISSUE8
#undef PACKB

    sl += __shfl_xor(sl, 16);
    sl += __shfl_xor(sl, 32);
    if (g == 0) Sp[(size_t)p * N_NODES + prow] = sl;

    __bf16* apb = accB + ((size_t)p * N_NODES + rowbase) * DOUT;
#pragma unroll
    for (int m = 0; m < 4; ++m)
#pragma unroll
        for (int r = 0; r < 4; ++r) {
            bf16x4 t2;
#pragma unroll
            for (int n = 0; n < 4; ++n) t2[n] = (__bf16)acc[m][n][r];
            *(bf16x4*)&apb[(size_t)(m * 16 + g * 4 + r) * DOUT + w * 64 + r15 * 4] = t2;
        }
}

// ---------------------------------------------------------------------------
// C: combine bf16 partials (permuted layout), softmax denom, leaky-relu,
// L2-normalize, +bias. Wave per row; un-permute on store.
template<int JS>
__global__ __launch_bounds__(256) void k_final(const __bf16* __restrict__ accB,
                                               const float* __restrict__ Sp,
                                               const float* __restrict__ bias,
                                               float* __restrict__ out) {
    int lane = threadIdx.x & 63, wv = threadIdx.x >> 6;
    int row = blockIdx.x * 4 + wv;
    float s = 0.f;
    f32x4 av = (f32x4){0.f, 0.f, 0.f, 0.f};
#pragma unroll
    for (int pp = 0; pp < JS; ++pp) {
        bf16x4 t = *(const bf16x4*)&accB[((size_t)pp * N_NODES + row) * DOUT + lane * 4];
#pragma unroll
        for (int j = 0; j < 4; ++j) av[j] += (float)t[j];
        s += Sp[(size_t)pp * N_NODES + row];
    }
    float inv = 1.0f / fmaxf(s, 1e-30f);
    f32x4 o;
#pragma unroll
    for (int j = 0; j < 4; ++j) {
        float x = av[j] * inv;
        o[j] = fmaxf(x, ALPHA * x);
    }
    float sq = o[0] * o[0] + o[1] * o[1] + o[2] * o[2] + o[3] * o[3];
#pragma unroll
    for (int m = 1; m < 64; m <<= 1) sq += __shfl_xor(sq, m);
    float innrm = 1.0f / fmaxf(sqrtf(sq), 1e-12f);
#pragma unroll
    for (int j = 0; j < 4; ++j) {
        int col = (lane >> 4) * 64 + j * 16 + (lane & 15);
        out[(size_t)row * DOUT + col] = o[j] * innrm + bias[col];
    }
}

// ---------------------------------------------------------------------------
extern "C" void kernel_launch(void* const* d_in, const int* in_sizes, int n_in,
                              void* d_out, int out_size, void* d_ws, size_t ws_size,
                              hipStream_t stream) {
    const float* node   = (const float*)d_in[0];
    const int*   adj    = (const int*)d_in[1];
    const float* weight = (const float*)d_in[2];
    const float* a      = (const float*)d_in[3];
    const float* bias   = (const float*)d_in[4];
    float* out = (float*)d_out;

    const size_t fixed  = 4522240;                 // wB 256K + vB 4M + Q/K 64K + kmax
    const size_t per_js = 32768 + (size_t)N_NODES * DOUT * 2;   // Sp + accB(bf16)
    int js = (ws_size >= fixed + 8 * per_js) ? 8 : 4;

    char* ws = (char*)d_ws;
    bf16x8*   wB      = (bf16x8*)(ws);
    bf16x8*   vB      = (bf16x8*)(ws + 262144);
    float*    Q       = (float*)(ws + 4456448);
    float*    K       = (float*)(ws + 4489216);
    unsigned* kmaxkey = (unsigned*)(ws + 4521984);
    float*    Sp      = (float*)(ws + fixed);
    __bf16*   accB    = (__bf16*)(ws + fixed + (size_t)js * 32768);

    k_repack_w<<<dim3(64),  dim3(256), 0, stream>>>(weight, wB, kmaxkey);
    k_gemm1f  <<<dim3(256), dim3(256), 0, stream>>>(node, wB, a, vB, Q, K, kmaxkey);
    if (js == 8) {
        k_attn<8><<<dim3(128 * 8), dim3(256), 0, stream>>>(adj, vB, Q, K, kmaxkey, accB, Sp);
        k_final<8><<<dim3(2048), dim3(256), 0, stream>>>(accB, Sp, bias, out);
    } else {
        k_attn<4><<<dim3(128 * 4), dim3(256), 0, stream>>>(adj, vB, Q, K, kmaxkey, accB, Sp);
        k_final<4><<<dim3(2048), dim3(256), 0, stream>>>(accB, Sp, bias, out);
    }
}